// Round 13
// baseline (204.781 us; speedup 1.0000x reference)
//
#include <hip/hip_runtime.h>
#include <cmath>

#define B_ 4
#define S_ 4096
#define D_ 1024
#define H_ 128
#define M_ (B_*S_)   // 16384 total rows
#define NQT 32       // S / 128 q-tiles (attn QBLK = 128)

typedef _Float16 half8 __attribute__((ext_vector_type(8)));
typedef _Float16 half4 __attribute__((ext_vector_type(4)));
typedef float f32x4 __attribute__((ext_vector_type(4)));
typedef float f32x16 __attribute__((ext_vector_type(16)));
typedef int i32x4 __attribute__((ext_vector_type(4)));

#define LOG2E 1.44269504088896340f

// async global->LDS, 16B per lane; LDS dest is wave-uniform base + lane*16
__device__ __forceinline__ void gload16(const void* g, void* l) {
    __builtin_amdgcn_global_load_lds(
        (const __attribute__((address_space(1))) unsigned int*)g,
        (__attribute__((address_space(3))) unsigned int*)l,
        16, 0, 0);
}

// ---------------------------------------------------------------------------
// Kernel 0: convert Wq/Wk/Wv (fp32) -> wh fp16 [3][H][D]  (order q,k,v)
// ---------------------------------------------------------------------------
__global__ __launch_bounds__(256) void conv_w(
    const float* __restrict__ Wq, const float* __restrict__ Wk,
    const float* __restrict__ Wv, _Float16* __restrict__ wh)
{
    const int idx  = blockIdx.x * 256 + threadIdx.x;
    const int base = idx * 8;                       // < 3*H*D = 393216
    const int m    = base >> 17;                    // H*D = 131072
    const int off  = base & ((H_ * D_) - 1);
    const float* src = (m == 0 ? Wq : m == 1 ? Wk : Wv) + off;
    const float4 a = ((const float4*)src)[0];
    const float4 c = ((const float4*)src)[1];
    half8 h = { (_Float16)a.x, (_Float16)a.y, (_Float16)a.z, (_Float16)a.w,
                (_Float16)c.x, (_Float16)c.y, (_Float16)c.z, (_Float16)c.w };
    *(half8*)(wh + base) = h;
}

// ---------------------------------------------------------------------------
// Kernel 1: QKV projection.  out = x @ W^T + b  (x fp32, W fp16 via conv_w)
// grid = (M/64, 3): y=0 -> q (scaled by log2e/sqrt(H)), y=1 -> k, y=2 -> v^T
// ---------------------------------------------------------------------------
__global__ __launch_bounds__(256, 3) void proj_kernel(
    const float* __restrict__ x, const _Float16* __restrict__ wh,
    const float* __restrict__ bq, const float* __restrict__ bk,
    const float* __restrict__ bv,
    _Float16* __restrict__ qh, _Float16* __restrict__ kh,
    _Float16* __restrict__ vt)
{
    __shared__ _Float16 Xs[2][64][72];     // +8 pad (reg-staged writes)
    __shared__ _Float16 Ws2[2][128][64];   // content at (r,blk)=G[r][blk^(r&7)]

    const int t = threadIdx.x;
    const int yb = blockIdx.y;
    const float* __restrict__ bias = (yb == 0) ? bq : (yb == 1) ? bk : bv;
    const int m0 = blockIdx.x * 64;
    const int w = t >> 6, lane = t & 63;
    const int lg = lane >> 4, lr = lane & 15;

    f32x4 acc[8];
    #pragma unroll
    for (int i = 0; i < 8; ++i) acc[i] = f32x4{0.f, 0.f, 0.f, 0.f};

    const int xrow = t >> 2, xc = (t & 3) * 16;   // X tile: 64x64, 16 f/thread
    const float* xbase = x + (size_t)(m0 + xrow) * D_ + xc;

    // W staging offsets (V-style swizzle): 4 gloads cover rows 32w..32w+32
    int wbyte[4];
    #pragma unroll
    for (int i = 0; i < 4; ++i) {
        const int wrow = 32 * w + 8 * i + (lane >> 3);
        const int wblk = (lane & 7) ^ (lane >> 3);
        wbyte[i] = (wrow * D_ + wblk * 8) * 2;
    }
    const char* whb = (const char*)(wh + (size_t)yb * H_ * D_);

    float4 xfA[4], xfB[4];

#define WISSUE(KT, BUF)                                                       \
    {                                                                         \
        const char* wsrc = whb + (KT) * (64 * 2);                             \
        _Pragma("unroll")                                                     \
        for (int i = 0; i < 4; ++i)                                           \
            gload16(wsrc + wbyte[i], &Ws2[BUF][32 * w + 8 * i][0]);           \
    }
#define XISSUE(KT, XS)                                                        \
    {                                                                         \
        const float4* xs_ = (const float4*)(xbase + (KT) * 64);               \
        _Pragma("unroll") for (int i = 0; i < 4; ++i) XS[i] = xs_[i];         \
    }
#define XWRITE(XS, BUF)                                                       \
    {                                                                         \
        _Pragma("unroll") for (int i = 0; i < 4; ++i) {                       \
            half4 h = { (_Float16)XS[i].x, (_Float16)XS[i].y,                 \
                        (_Float16)XS[i].z, (_Float16)XS[i].w };               \
            *(half4*)&Xs[BUF][xrow][xc + 4 * i] = h;                          \
        }                                                                     \
    }
#define PMFMA(BUF)                                                            \
    {                                                                         \
        _Pragma("unroll") for (int kk = 0; kk < 2; ++kk) {                    \
            half8 a = *(const half8*)&Xs[BUF][w * 16 + lr][kk * 32 + 8 * lg]; \
            _Pragma("unroll") for (int ni = 0; ni < 8; ++ni) {                \
                half8 bfr = *(const half8*)&Ws2[BUF][ni * 16 + lr]            \
                                [((4 * kk + lg) ^ (lr & 7)) * 8];             \
                acc[ni] = __builtin_amdgcn_mfma_f32_16x16x32_f16(a, bfr, acc[ni], 0, 0, 0); \
            }                                                                 \
        }                                                                     \
    }

    WISSUE(0, 0)
    XISSUE(0, xfA)
    XISSUE(1, xfB)
    XWRITE(xfA, 0)
    __syncthreads();   // drains W0 gloads + X0 writes

    for (int kt = 0; kt < 16; kt += 2) {
        // ---- even tile kt (buf 0) ----
        WISSUE(kt + 1, 1)
        if (kt + 2 < 16) XISSUE(kt + 2, xfA)
        PMFMA(0)
        XWRITE(xfB, 1)
        __syncthreads();
        // ---- odd tile kt+1 (buf 1) ----
        if (kt + 2 < 16) WISSUE(kt + 2, 0)
        if (kt + 3 < 16) XISSUE(kt + 3, xfB)
        PMFMA(1)
        if (kt + 2 < 16) XWRITE(xfA, 0)
        __syncthreads();
    }
#undef WISSUE
#undef XISSUE
#undef XWRITE
#undef PMFMA

    // q scale folds 1/sqrt(128) AND log2(e) (softmax runs in exp2 domain)
    const float qscale = 0.08838834764831845f * LOG2E;
    const int rowb = m0 + w * 16 + lg * 4;   // C/D: row = 4*(lane>>4)+r, col = ni*16+lr
    #pragma unroll
    for (int ni = 0; ni < 8; ++ni) {
        const int col = ni * 16 + lr;
        const float bval = bias[col];
        if (yb == 0) {
            #pragma unroll
            for (int r = 0; r < 4; ++r)
                qh[(size_t)(rowb + r) * H_ + col] = (_Float16)((acc[ni][r] + bval) * qscale);
        } else if (yb == 1) {
            #pragma unroll
            for (int r = 0; r < 4; ++r)
                kh[(size_t)(rowb + r) * H_ + col] = (_Float16)(acc[ni][r] + bval);
        } else {
            const int bb = rowb >> 12, s0 = rowb & (S_ - 1);
            half4 h;
            #pragma unroll
            for (int r = 0; r < 4; ++r) h[r] = (_Float16)(acc[ni][r] + bval);
            *(half4*)&vt[(size_t)bb * H_ * S_ + (size_t)col * S_ + s0] = h;
        }
    }
}

// ---------------------------------------------------------------------------
// Kernel 2: flash attention, 32x32x16 core (R9/R12-verified math), phase-
// overlapped regions: per region, softmax(t) then a FUSED MFMA cluster
// [PV(t) + QK(t+1)] (independent chains -> dense MFMA pipe; ds_reads hoist
// under the softmax VALU chain). K/V each double-buffered; staging issued
// 2-3 tiles ahead with counted vmcnt (never drained to 0 in-loop).
// ---------------------------------------------------------------------------
__device__ __forceinline__ void qk_only(
    const _Float16 (&Kb)[64][128], const half8 (&qf)[8], f32x16 (&sf)[2], int lane)
{
    const int l31 = lane & 31, l7 = lane & 7, hi = lane >> 5;
    #pragma unroll
    for (int nb = 0; nb < 2; ++nb)
        #pragma unroll
        for (int r = 0; r < 16; ++r) sf[nb][r] = 0.f;
    __builtin_amdgcn_s_setprio(1);
    #pragma unroll
    for (int kt = 0; kt < 8; ++kt)
        #pragma unroll
        for (int nb = 0; nb < 2; ++nb) {
            half8 kb = *(const half8*)&Kb[nb * 32 + l31][((2 * kt + hi) ^ l7) * 8];
            sf[nb] = __builtin_amdgcn_mfma_f32_32x32x16_f16(kb, qf[kt], sf[nb], 0, 0, 0);
        }
    __builtin_amdgcn_s_setprio(0);
}

template <bool HAS_NEXT>
__device__ __forceinline__ void region_compute(
    const _Float16 (&Kn)[64][128], const _Float16 (&Vc)[128][64],
    const half8 (&qf)[8], f32x16 (&sfin)[2], f32x16 (&sfout)[2],
    f32x16 (&acc2)[4], float& m_, float& l_, int muse, int lane)
{
    const unsigned long long bz = __ballot(muse == 0);
    const int l31 = lane & 31, l7 = lane & 7, hi = lane >> 5;

    if (bz) {   // padding mask (reference: where(mask==0, -1e9))
        #pragma unroll
        for (int nb = 0; nb < 2; ++nb)
            #pragma unroll
            for (int r = 0; r < 16; ++r) {
                const int kv = nb * 32 + (r & 3) + 8 * (r >> 2) + 4 * hi;
                if ((bz >> kv) & 1ull) sfin[nb][r] = -3e9f;
            }
    }
    // online softmax in exp2 domain; TREE max (depth 5)
    float tv[16];
    #pragma unroll
    for (int r = 0; r < 16; ++r) tv[r] = fmaxf(sfin[0][r], sfin[1][r]);
    #pragma unroll
    for (int off = 8; off > 0; off >>= 1)
        #pragma unroll
        for (int r = 0; r < off; ++r) tv[r] = fmaxf(tv[r], tv[r + off]);
    float tmax = fmaxf(tv[0], __shfl_xor(tv[0], 32));
    if (!__all(tmax <= m_ + 8.f)) {   // defer-max: skip rescale when safe
        const float mn  = fmaxf(m_, tmax);
        const float scl = exp2f(m_ - mn);
        m_ = mn; l_ *= scl;
        #pragma unroll
        for (int hb = 0; hb < 4; ++hb) acc2[hb] *= scl;
    }
    #pragma unroll
    for (int nb = 0; nb < 2; ++nb)
        #pragma unroll
        for (int r = 0; r < 16; ++r) sfin[nb][r] = exp2f(sfin[nb][r] - m_);
    // TREE sum
    float sv[16];
    #pragma unroll
    for (int r = 0; r < 16; ++r) sv[r] = sfin[0][r] + sfin[1][r];
    #pragma unroll
    for (int off = 8; off > 0; off >>= 1)
        #pragma unroll
        for (int r = 0; r < off; ++r) sv[r] += sv[r + off];
    l_ += sv[0] + __shfl_xor(sv[0], 32);

    // pack P pairs: pkw[nb][i] holds kv = 32nb + 8*(i>>1) + 4hi + 2*(i&1), +1
    int pkw[2][8];
    #pragma unroll
    for (int nb = 0; nb < 2; ++nb)
        #pragma unroll
        for (int i = 0; i < 8; ++i) {
            auto h2 = __builtin_amdgcn_cvt_pkrtz(sfin[nb][2 * i], sfin[nb][2 * i + 1]);
            pkw[nb][i] = __builtin_bit_cast(int, h2);
        }
    // exchange across lane halves (direction-unambiguous shfl_xor)
    #pragma unroll
    for (int nb = 0; nb < 2; ++nb)
        #pragma unroll
        for (int hf = 0; hf < 2; ++hf) {
            const int i0 = hf * 4;
            const int sA = hi ? pkw[nb][i0 + 0] : pkw[nb][i0 + 2];
            const int sB = hi ? pkw[nb][i0 + 1] : pkw[nb][i0 + 3];
            const int rA = __shfl_xor(sA, 32);   // lo<-hi's w0 ; hi<-lo's w2
            const int rB = __shfl_xor(sB, 32);   // lo<-hi's w1 ; hi<-lo's w3
            const int n0 = hi ? rA : pkw[nb][i0 + 0];
            const int n1 = hi ? rB : pkw[nb][i0 + 1];
            const int n2 = hi ? pkw[nb][i0 + 2] : rA;
            const int n3 = hi ? pkw[nb][i0 + 3] : rB;
            pkw[nb][i0 + 0] = n0; pkw[nb][i0 + 1] = n1;
            pkw[nb][i0 + 2] = n2; pkw[nb][i0 + 3] = n3;
        }

    // fused MFMA cluster: PV(t) [+ QK(t+1) when HAS_NEXT] — independent chains
    if (HAS_NEXT) {
        #pragma unroll
        for (int nb = 0; nb < 2; ++nb)
            #pragma unroll
            for (int r = 0; r < 16; ++r) sfout[nb][r] = 0.f;
    }
    __builtin_amdgcn_s_setprio(1);
    #pragma unroll
    for (int s = 0; s < 4; ++s) {
        if (HAS_NEXT) {
            #pragma unroll
            for (int k2 = 0; k2 < 2; ++k2) {
                const int kt = 2 * s + k2;
                #pragma unroll
                for (int nb = 0; nb < 2; ++nb) {
                    half8 kb = *(const half8*)&Kn[nb * 32 + l31][((2 * kt + hi) ^ l7) * 8];
                    sfout[nb] = __builtin_amdgcn_mfma_f32_32x32x16_f16(kb, qf[kt], sfout[nb], 0, 0, 0);
                }
            }
        }
        const int nb = s >> 1, hf = s & 1;
        const half8 pb = __builtin_bit_cast(half8,
            i32x4{ pkw[nb][hf * 4 + 0], pkw[nb][hf * 4 + 1],
                   pkw[nb][hf * 4 + 2], pkw[nb][hf * 4 + 3] });
        #pragma unroll
        for (int hb = 0; hb < 4; ++hb) {
            half8 vb = *(const half8*)&Vc[hb * 32 + l31][((2 * s + hi) ^ l7) * 8];
            acc2[hb] = __builtin_amdgcn_mfma_f32_32x32x16_f16(vb, pb, acc2[hb], 0, 0, 0);
        }
    }
    __builtin_amdgcn_s_setprio(0);
}

__global__ __launch_bounds__(256, 2) void attn_kernel(
    const _Float16* __restrict__ qh, const _Float16* __restrict__ kh,
    const _Float16* __restrict__ vt, const int* __restrict__ mask,
    float* __restrict__ pout, float* __restrict__ pm, float* __restrict__ pl,
    const int nsplit)
{
    __shared__ _Float16 Ks[2][64][128];   // [buf][kv][d]; content swizzled
    __shared__ _Float16 Vs[2][128][64];   // [buf][h][kv]

    const int t = threadIdx.x;
    const int id = blockIdx.x;
    // L2-locality swizzle: each XCD owns ncombo/8 (b,split) combos.
    int qt, sp, b;
    const int ncombo = B_ * nsplit;
    if ((ncombo & 7) == 0) {
        const int per_xcd = ncombo >> 3;
        const int j = id >> 3;
        qt = j & (NQT - 1);
        const int combo = (id & 7) * per_xcd + (j >> 5);   // log2(NQT)=5
        sp = combo % nsplit; b = combo / nsplit;
    } else {
        qt = id & (NQT - 1);
        const int rest = id >> 5;
        sp = rest % nsplit; b = rest / nsplit;
    }
    const int q0 = qt * 128;
    const int w = t >> 6, lane = t & 63;
    const int l31 = lane & 31, hi = lane >> 5;
    const int kvlen  = S_ / nsplit;
    const int iters  = kvlen >> 6;   // even, >= 8
    const int kvbase = sp * kvlen;

    // per-lane byte offsets of the SWIZZLED global source (loop-invariant)
    int kbyte[4], vbyte[4];
    #pragma unroll
    for (int i = 0; i < 4; ++i) {
        const int krow = 16 * w + 4 * i + (lane >> 4);
        const int kblk = (lane & 15) ^ (krow & 7);
        kbyte[i] = (krow * H_ + kblk * 8) * 2;
        const int vrow = 32 * w + 8 * i + (lane >> 3);
        const int vblk = (lane & 7) ^ (lane >> 3);   // vrow&7 == lane>>3
        vbyte[i] = (vrow * S_ + vblk * 8) * 2;
    }
    const char* kbase_b = (const char*)(kh + (size_t)(b * S_ + kvbase) * H_);
    const char* vbase_b = (const char*)(vt + (size_t)b * H_ * S_ + kvbase);
    const char* mbase_b = (const char*)(mask + b * S_ + kvbase + lane);

#define ISSUE_K(IT, NB)                                                       \
    {                                                                         \
        const char* kb_t = kbase_b + (size_t)(IT) * (64 * H_ * 2);            \
        _Pragma("unroll")                                                     \
        for (int i = 0; i < 4; ++i)                                           \
            gload16(kb_t + kbyte[i], &Ks[NB][16 * w + 4 * i][0]);             \
    }
#define ISSUE_V(IT, NB)                                                       \
    {                                                                         \
        const char* vb_t = vbase_b + (size_t)(IT) * (64 * 2);                 \
        _Pragma("unroll")                                                     \
        for (int i = 0; i < 4; ++i)                                           \
            gload16(vb_t + vbyte[i], &Vs[NB][32 * w + 8 * i][0]);             \
    }
#define WAITN(N)  asm volatile("s_waitcnt vmcnt(" #N ")" ::: "memory")
#define BAR       asm volatile("s_barrier" ::: "memory")

    // ---- prologue: register loads FIRST (oldest), then staging ----
    half8 qf[8];   // lane owns q-row (q0 + 32w + l31); d = 16kt + 8hi + j
    {
        const _Float16* qp = qh + (size_t)(b * S_ + q0 + 32 * w + l31) * H_ + 8 * hi;
        #pragma unroll
        for (int kt = 0; kt < 8; ++kt) qf[kt] = *(const half8*)(qp + 16 * kt);
    }
    int mA = *(const int*)(mbase_b);            // mask(0)
    int mB = *(const int*)(mbase_b + 256);      // mask(1)

    ISSUE_K(0, 0) ISSUE_K(1, 1) ISSUE_V(0, 0) ISSUE_V(1, 1)

    float m_ = -1e30f, l_ = 0.f;
    f32x16 acc2[4];
    #pragma unroll
    for (int hb = 0; hb < 4; ++hb)
        #pragma unroll
        for (int r = 0; r < 16; ++r) acc2[hb][r] = 0.f;

    f32x16 sfA[2], sfB[2];

    WAITN(12);              // K0 done (K1,V0,V1 = 12 newest keep flying)
    BAR;                    // Ks[0] ready
    qk_only(Ks[0], qf, sfA, lane);
    BAR;                    // Ks[0] consumed (K-read)
    ISSUE_K(2, 0)
    WAITN(8);               // K1,V0 done (V1,K2 = 8 newest keep flying)

    for (int it = 0; it < iters; it += 2) {
        // ---- region t = it (even): softmax sfA; PV from Vs[0]; QK Ks[1]->sfB
        BAR;                // certifies K(it+1) in Ks[1], V(it) in Vs[0]
        region_compute<true>(Ks[1], Vs[0], qf, sfA, sfB, acc2, m_, l_, mA, lane);
        BAR;                // Vs[0] + Ks[1] consumed
        if (it + 2 < iters) mA = *(const int*)(mbase_b + (size_t)(it + 2) * 256);
        if (it + 2 < iters) ISSUE_V(it + 2, 0)
        if (it + 3 < iters) ISSUE_K(it + 3, 1)
        WAITN(9);           // all older stagings done; this region's 9 fly
        // ---- region t = it+1 (odd): softmax sfB; PV from Vs[1]; QK Ks[0]->sfA
        BAR;                // certifies K(it+2) in Ks[0], V(it+1) in Vs[1]
        if (it + 2 < iters)
            region_compute<true>(Ks[0], Vs[1], qf, sfB, sfA, acc2, m_, l_, mB, lane);
        else
            region_compute<false>(Ks[0], Vs[1], qf, sfB, sfA, acc2, m_, l_, mB, lane);
        BAR;                // Vs[1] + Ks[0] consumed
        if (it + 3 < iters) mB = *(const int*)(mbase_b + (size_t)(it + 3) * 256);
        if (it + 3 < iters) ISSUE_V(it + 3, 1)
        if (it + 4 < iters) ISSUE_K(it + 4, 0)
        WAITN(9);
    }
#undef ISSUE_K
#undef ISSUE_V
#undef WAITN
#undef BAR

    // store unnormalized partials: lane writes its q-row, 64 h-values
    const int qrow = b * S_ + q0 + 32 * w + l31;
    float* op = pout + (size_t)(sp * M_ + qrow) * H_;
    #pragma unroll
    for (int hb = 0; hb < 4; ++hb)
        #pragma unroll
        for (int i = 0; i < 8; ++i) {
            const int h = hb * 32 + 2 * (i & 1) + 8 * (i >> 1) + 4 * hi;
            float2 v2 = make_float2(acc2[hb][2 * i], acc2[hb][2 * i + 1]);
            *(float2*)(op + h) = v2;
        }
    if (hi == 0) {
        pm[sp * M_ + qrow] = m_;
        pl[sp * M_ + qrow] = l_;
    }
}

// ---------------------------------------------------------------------------
// Kernel 3: combine KV-split partials and normalize (exp2 domain).
// ---------------------------------------------------------------------------
__global__ __launch_bounds__(256) void combine_kernel(
    const float* __restrict__ pout, const float* __restrict__ pm,
    const float* __restrict__ pl, float* __restrict__ out, const int nsplit)
{
    const int idx = blockIdx.x * 256 + threadIdx.x;
    const int row = idx >> 7;          // global row
    const int h   = idx & (H_ - 1);
    float M = -1e30f;
    for (int sp = 0; sp < nsplit; ++sp) M = fmaxf(M, pm[sp * M_ + row]);
    float Z = 0.f, o = 0.f;
    for (int sp = 0; sp < nsplit; ++sp) {
        const float wgt = exp2f(pm[sp * M_ + row] - M);
        Z += wgt * pl[sp * M_ + row];
        o += wgt * pout[(size_t)(sp * M_ + row) * H_ + h];
    }
    out[idx] = o / Z;
}

// ---------------------------------------------------------------------------
extern "C" void kernel_launch(void* const* d_in, const int* in_sizes, int n_in,
                              void* d_out, int out_size, void* d_ws, size_t ws_size,
                              hipStream_t stream)
{
    (void)in_sizes; (void)n_in; (void)out_size;
    // setup_inputs order: inputs, Wk, bk, Wq, bq, Wv, bv, padding_mask
    const float* x  = (const float*)d_in[0];
    const float* Wk = (const float*)d_in[1];
    const float* bk = (const float*)d_in[2];
    const float* Wq = (const float*)d_in[3];
    const float* bq = (const float*)d_in[4];
    const float* Wv = (const float*)d_in[5];
    const float* bv = (const float*)d_in[6];
    const int* mask = (const int*)d_in[7];

    char* ws = (char*)d_ws;
    const size_t qkvBytes = (size_t)M_ * H_ * sizeof(_Float16);   // 4 MB each
    _Float16* qh = (_Float16*)ws;
    _Float16* kh = (_Float16*)(ws + qkvBytes);
    _Float16* vt = (_Float16*)(ws + 2 * qkvBytes);                // [B][H][S]
    _Float16* wh = (_Float16*)(ws + 3 * qkvBytes);                // [3][H][D]
    const size_t whBytes = (size_t)3 * H_ * D_ * sizeof(_Float16);
    char* rest = ws + 3 * qkvBytes + whBytes;

    int nsplit = 4;   // proven partials traffic (46 MB); grid 512
    const size_t perSplit = (size_t)M_ * H_ * 4 + 2 * (size_t)M_ * 4;
    while (nsplit > 1 &&
           3 * qkvBytes + whBytes + (size_t)nsplit * perSplit > ws_size) nsplit >>= 1;

    float* pout = (float*)rest;
    float* pm   = (float*)(rest + (size_t)nsplit * M_ * H_ * 4);
    float* pl   = pm + (size_t)nsplit * M_;

    conv_w<<<dim3(3 * H_ * D_ / (256 * 8)), 256, 0, stream>>>(Wq, Wk, Wv, wh);
    proj_kernel<<<dim3(M_ / 64, 3), 256, 0, stream>>>(x, wh, bq, bk, bv, qh, kh, vt);
    attn_kernel<<<dim3(NQT * B_ * nsplit), 256, 0, stream>>>(qh, kh, vt, mask, pout, pm, pl, nsplit);
    combine_kernel<<<dim3(M_ * H_ / 256), 256, 0, stream>>>(pout, pm, pl, (float*)d_out, nsplit);
}

// Round 14
// 114.371 us; speedup vs baseline: 1.7905x; 1.7905x over previous
//
#include <hip/hip_runtime.h>
#include <cmath>

#define B_ 4
#define S_ 4096
#define D_ 1024
#define H_ 128
#define M_ (B_*S_)   // 16384 total rows
#define NQT 32       // S / 128 q-tiles (attn QBLK = 128)

typedef _Float16 half8 __attribute__((ext_vector_type(8)));
typedef _Float16 half4 __attribute__((ext_vector_type(4)));
typedef float f32x4 __attribute__((ext_vector_type(4)));
typedef float f32x16 __attribute__((ext_vector_type(16)));
typedef int i32x4 __attribute__((ext_vector_type(4)));

#define LOG2E 1.44269504088896340f

// async global->LDS, 16B per lane; LDS dest is wave-uniform base + lane*16
__device__ __forceinline__ void gload16(const void* g, void* l) {
    __builtin_amdgcn_global_load_lds(
        (const __attribute__((address_space(1))) unsigned int*)g,
        (__attribute__((address_space(3))) unsigned int*)l,
        16, 0, 0);
}

// ---------------------------------------------------------------------------
// Kernel 0: convert Wq/Wk/Wv (fp32) -> wh fp16 [3][H][D]  (order q,k,v)
// ---------------------------------------------------------------------------
__global__ __launch_bounds__(256) void conv_w(
    const float* __restrict__ Wq, const float* __restrict__ Wk,
    const float* __restrict__ Wv, _Float16* __restrict__ wh)
{
    const int idx  = blockIdx.x * 256 + threadIdx.x;
    const int base = idx * 8;                       // < 3*H*D = 393216
    const int m    = base >> 17;                    // H*D = 131072
    const int off  = base & ((H_ * D_) - 1);
    const float* src = (m == 0 ? Wq : m == 1 ? Wk : Wv) + off;
    const float4 a = ((const float4*)src)[0];
    const float4 c = ((const float4*)src)[1];
    half8 h = { (_Float16)a.x, (_Float16)a.y, (_Float16)a.z, (_Float16)a.w,
                (_Float16)c.x, (_Float16)c.y, (_Float16)c.z, (_Float16)c.w };
    *(half8*)(wh + base) = h;
}

// ---------------------------------------------------------------------------
// Kernel 1: QKV projection.  out = x @ W^T + b  (x fp32, W fp16 via conv_w)
// grid = (M/64, 3): y=0 -> q (scaled by log2e/sqrt(H)), y=1 -> k, y=2 -> v^T
// ---------------------------------------------------------------------------
__global__ __launch_bounds__(256, 3) void proj_kernel(
    const float* __restrict__ x, const _Float16* __restrict__ wh,
    const float* __restrict__ bq, const float* __restrict__ bk,
    const float* __restrict__ bv,
    _Float16* __restrict__ qh, _Float16* __restrict__ kh,
    _Float16* __restrict__ vt)
{
    __shared__ _Float16 Xs[2][64][72];     // +8 pad (reg-staged writes)
    __shared__ _Float16 Ws2[2][128][64];   // content at (r,blk)=G[r][blk^(r&7)]

    const int t = threadIdx.x;
    const int yb = blockIdx.y;
    const float* __restrict__ bias = (yb == 0) ? bq : (yb == 1) ? bk : bv;
    const int m0 = blockIdx.x * 64;
    const int w = t >> 6, lane = t & 63;
    const int lg = lane >> 4, lr = lane & 15;

    f32x4 acc[8];
    #pragma unroll
    for (int i = 0; i < 8; ++i) acc[i] = f32x4{0.f, 0.f, 0.f, 0.f};

    const int xrow = t >> 2, xc = (t & 3) * 16;   // X tile: 64x64, 16 f/thread
    const float* xbase = x + (size_t)(m0 + xrow) * D_ + xc;

    // W staging offsets (V-style swizzle): 4 gloads cover rows 32w..32w+32
    int wbyte[4];
    #pragma unroll
    for (int i = 0; i < 4; ++i) {
        const int wrow = 32 * w + 8 * i + (lane >> 3);
        const int wblk = (lane & 7) ^ (lane >> 3);
        wbyte[i] = (wrow * D_ + wblk * 8) * 2;
    }
    const char* whb = (const char*)(wh + (size_t)yb * H_ * D_);

    float4 xfA[4], xfB[4];

#define WISSUE(KT, BUF)                                                       \
    {                                                                         \
        const char* wsrc = whb + (KT) * (64 * 2);                             \
        _Pragma("unroll")                                                     \
        for (int i = 0; i < 4; ++i)                                           \
            gload16(wsrc + wbyte[i], &Ws2[BUF][32 * w + 8 * i][0]);           \
    }
#define XISSUE(KT, XS)                                                        \
    {                                                                         \
        const float4* xs_ = (const float4*)(xbase + (KT) * 64);               \
        _Pragma("unroll") for (int i = 0; i < 4; ++i) XS[i] = xs_[i];         \
    }
#define XWRITE(XS, BUF)                                                       \
    {                                                                         \
        _Pragma("unroll") for (int i = 0; i < 4; ++i) {                       \
            half4 h = { (_Float16)XS[i].x, (_Float16)XS[i].y,                 \
                        (_Float16)XS[i].z, (_Float16)XS[i].w };               \
            *(half4*)&Xs[BUF][xrow][xc + 4 * i] = h;                          \
        }                                                                     \
    }
#define PMFMA(BUF)                                                            \
    {                                                                         \
        _Pragma("unroll") for (int kk = 0; kk < 2; ++kk) {                    \
            half8 a = *(const half8*)&Xs[BUF][w * 16 + lr][kk * 32 + 8 * lg]; \
            _Pragma("unroll") for (int ni = 0; ni < 8; ++ni) {                \
                half8 bfr = *(const half8*)&Ws2[BUF][ni * 16 + lr]            \
                                [((4 * kk + lg) ^ (lr & 7)) * 8];             \
                acc[ni] = __builtin_amdgcn_mfma_f32_16x16x32_f16(a, bfr, acc[ni], 0, 0, 0); \
            }                                                                 \
        }                                                                     \
    }

    WISSUE(0, 0)
    XISSUE(0, xfA)
    XISSUE(1, xfB)
    XWRITE(xfA, 0)
    __syncthreads();   // drains W0 gloads + X0 writes

    for (int kt = 0; kt < 16; kt += 2) {
        // ---- even tile kt (buf 0) ----
        WISSUE(kt + 1, 1)
        if (kt + 2 < 16) XISSUE(kt + 2, xfA)
        PMFMA(0)
        XWRITE(xfB, 1)
        __syncthreads();
        // ---- odd tile kt+1 (buf 1) ----
        if (kt + 2 < 16) WISSUE(kt + 2, 0)
        if (kt + 3 < 16) XISSUE(kt + 3, xfB)
        PMFMA(1)
        if (kt + 2 < 16) XWRITE(xfA, 0)
        __syncthreads();
    }
#undef WISSUE
#undef XISSUE
#undef XWRITE
#undef PMFMA

    // q scale folds 1/sqrt(128) AND log2(e) (softmax runs in exp2 domain)
    const float qscale = 0.08838834764831845f * LOG2E;
    const int rowb = m0 + w * 16 + lg * 4;   // C/D: row = 4*(lane>>4)+r, col = ni*16+lr
    #pragma unroll
    for (int ni = 0; ni < 8; ++ni) {
        const int col = ni * 16 + lr;
        const float bval = bias[col];
        if (yb == 0) {
            #pragma unroll
            for (int r = 0; r < 4; ++r)
                qh[(size_t)(rowb + r) * H_ + col] = (_Float16)((acc[ni][r] + bval) * qscale);
        } else if (yb == 1) {
            #pragma unroll
            for (int r = 0; r < 4; ++r)
                kh[(size_t)(rowb + r) * H_ + col] = (_Float16)(acc[ni][r] + bval);
        } else {
            const int bb = rowb >> 12, s0 = rowb & (S_ - 1);
            half4 h;
            #pragma unroll
            for (int r = 0; r < 4; ++r) h[r] = (_Float16)(acc[ni][r] + bval);
            *(half4*)&vt[(size_t)bb * H_ * S_ + (size_t)col * S_ + s0] = h;
        }
    }
}

// ---------------------------------------------------------------------------
// Kernel 2: flash attention, 32x32x16 core (R9/R12-verified math).
// KVBLK=128 staged per sync event (K[128][128] + V[128][128] = 64 KB single
// buffer): HALF the barrier/stage events of R9 at identical staged bytes.
// The proven 64-kv compute runs twice per staged tile. Swizzle note: XOR key
// (row&7) touches only block-bits 0-2, so 16-block rows keep the original
// write/read formulas and the kv/d half split (block-bit 3) is preserved.
// ---------------------------------------------------------------------------
__device__ __forceinline__ void attn_tile32(
    const _Float16 (&Kb)[64][128], const _Float16 (&Vb)[128][128], int kvh,
    const half8 (&qf)[8], f32x16 (&acc2)[4], float& m_, float& l_,
    int muse, int lane)
{
    const unsigned long long bz = __ballot(muse == 0);
    const int l31 = lane & 31, l7 = lane & 7, hi = lane >> 5;

    // S^T = K Q^T : sf[nb][r] = S'[kv = 32nb + (r&3)+8*(r>>2)+4hi][q = l31]
    f32x16 sf[2];
    #pragma unroll
    for (int nb = 0; nb < 2; ++nb)
        #pragma unroll
        for (int r = 0; r < 16; ++r) sf[nb][r] = 0.f;
    __builtin_amdgcn_s_setprio(1);
    #pragma unroll
    for (int kt = 0; kt < 8; ++kt) {
        #pragma unroll
        for (int nb = 0; nb < 2; ++nb) {
            half8 kb = *(const half8*)&Kb[nb * 32 + l31][((2 * kt + hi) ^ l7) * 8];
            sf[nb] = __builtin_amdgcn_mfma_f32_32x32x16_f16(kb, qf[kt], sf[nb], 0, 0, 0);
        }
    }
    __builtin_amdgcn_s_setprio(0);
    if (bz) {   // padding mask (reference: where(mask==0, -1e9))
        #pragma unroll
        for (int nb = 0; nb < 2; ++nb)
            #pragma unroll
            for (int r = 0; r < 16; ++r) {
                const int kv = nb * 32 + (r & 3) + 8 * (r >> 2) + 4 * hi;
                if ((bz >> kv) & 1ull) sf[nb][r] = -3e9f;
            }
    }
    // online softmax in exp2 domain; TREE max (depth 5)
    float tv[16];
    #pragma unroll
    for (int r = 0; r < 16; ++r) tv[r] = fmaxf(sf[0][r], sf[1][r]);
    #pragma unroll
    for (int off = 8; off > 0; off >>= 1)
        #pragma unroll
        for (int r = 0; r < off; ++r) tv[r] = fmaxf(tv[r], tv[r + off]);
    float tmax = fmaxf(tv[0], __shfl_xor(tv[0], 32));
    if (!__all(tmax <= m_ + 8.f)) {   // defer-max: skip rescale when safe
        const float mn  = fmaxf(m_, tmax);
        const float scl = exp2f(m_ - mn);
        m_ = mn; l_ *= scl;
        #pragma unroll
        for (int hb = 0; hb < 4; ++hb) acc2[hb] *= scl;
    }
    #pragma unroll
    for (int nb = 0; nb < 2; ++nb)
        #pragma unroll
        for (int r = 0; r < 16; ++r) sf[nb][r] = exp2f(sf[nb][r] - m_);
    // TREE sum
    float sv[16];
    #pragma unroll
    for (int r = 0; r < 16; ++r) sv[r] = sf[0][r] + sf[1][r];
    #pragma unroll
    for (int off = 8; off > 0; off >>= 1)
        #pragma unroll
        for (int r = 0; r < off; ++r) sv[r] += sv[r + off];
    l_ += sv[0] + __shfl_xor(sv[0], 32);

    // pack P pairs: pkw[nb][i] holds kv = 32nb + 8*(i>>1) + 4hi + 2*(i&1), +1
    int pkw[2][8];
    #pragma unroll
    for (int nb = 0; nb < 2; ++nb)
        #pragma unroll
        for (int i = 0; i < 8; ++i) {
            auto h2 = __builtin_amdgcn_cvt_pkrtz(sf[nb][2 * i], sf[nb][2 * i + 1]);
            pkw[nb][i] = __builtin_bit_cast(int, h2);
        }
    // exchange across lane halves (direction-unambiguous shfl_xor):
    // lo lanes keep w0,w1 and receive other-half's w0,w1 as w2,w3;
    // hi lanes keep w2,w3 and receive other-half's w2,w3 as w0,w1.
    #pragma unroll
    for (int nb = 0; nb < 2; ++nb)
        #pragma unroll
        for (int hf = 0; hf < 2; ++hf) {
            const int i0 = hf * 4;
            const int sA = hi ? pkw[nb][i0 + 0] : pkw[nb][i0 + 2];
            const int sB = hi ? pkw[nb][i0 + 1] : pkw[nb][i0 + 3];
            const int rA = __shfl_xor(sA, 32);   // lo<-hi's w0 ; hi<-lo's w2
            const int rB = __shfl_xor(sB, 32);   // lo<-hi's w1 ; hi<-lo's w3
            const int n0 = hi ? rA : pkw[nb][i0 + 0];
            const int n1 = hi ? rB : pkw[nb][i0 + 1];
            const int n2 = hi ? pkw[nb][i0 + 2] : rA;
            const int n3 = hi ? pkw[nb][i0 + 3] : rB;
            pkw[nb][i0 + 0] = n0; pkw[nb][i0 + 1] = n1;
            pkw[nb][i0 + 2] = n2; pkw[nb][i0 + 3] = n3;
        }
    // O^T += V^T P^T : acc2[hb][r] = O[q=l31][h = 32hb + (r&3)+8*(r>>2)+4hi]
    __builtin_amdgcn_s_setprio(1);
    #pragma unroll
    for (int s = 0; s < 4; ++s) {
        const int nb = s >> 1, hf = s & 1;
        const half8 pb = __builtin_bit_cast(half8,
            i32x4{ pkw[nb][hf * 4 + 0], pkw[nb][hf * 4 + 1],
                   pkw[nb][hf * 4 + 2], pkw[nb][hf * 4 + 3] });
        #pragma unroll
        for (int hb = 0; hb < 4; ++hb) {
            half8 vb = *(const half8*)&Vb[hb * 32 + l31][kvh * 64 + ((2 * s + hi) ^ l7) * 8];
            acc2[hb] = __builtin_amdgcn_mfma_f32_32x32x16_f16(vb, pb, acc2[hb], 0, 0, 0);
        }
    }
    __builtin_amdgcn_s_setprio(0);
}

__global__ __launch_bounds__(256, 2) void attn_kernel(
    const _Float16* __restrict__ qh, const _Float16* __restrict__ kh,
    const _Float16* __restrict__ vt, const int* __restrict__ mask,
    float* __restrict__ pout, float* __restrict__ pm, float* __restrict__ pl,
    const int nsplit)
{
    __shared__ _Float16 Ks[128][128];   // [kv][d]; content swizzled, 32 KB
    __shared__ _Float16 Vs[128][128];   // [h][kv]; content swizzled, 32 KB

    const int t = threadIdx.x;
    const int id = blockIdx.x;
    // L2-locality swizzle: each XCD owns ncombo/8 (b,split) combos.
    int qt, sp, b;
    const int ncombo = B_ * nsplit;
    if ((ncombo & 7) == 0) {
        const int per_xcd = ncombo >> 3;
        const int j = id >> 3;
        qt = j & (NQT - 1);
        const int combo = (id & 7) * per_xcd + (j >> 5);   // log2(NQT)=5
        sp = combo % nsplit; b = combo / nsplit;
    } else {
        qt = id & (NQT - 1);
        const int rest = id >> 5;
        sp = rest % nsplit; b = rest / nsplit;
    }
    const int q0 = qt * 128;
    const int w = t >> 6, lane = t & 63;
    const int l31 = lane & 31, hi = lane >> 5;
    const int kvlen  = S_ / nsplit;
    const int iters2 = kvlen >> 7;   // 128-kv tiles (8 at nsplit=4)
    const int kvbase = sp * kvlen;

    // per-lane byte offsets of the SWIZZLED global source (loop-invariant).
    // 8 instrs each: wave w stages rows 32w..32w+31 (4 rows per instr,
    // 16 x 16B blocks per 256B row; XOR key row&7 preserves block-bit 3).
    int kbyte[8], vbyte[8];
    #pragma unroll
    for (int i = 0; i < 8; ++i) {
        const int krow = 32 * w + 4 * i + (lane >> 4);     // kv row
        const int kblk = (lane & 15) ^ (krow & 7);
        kbyte[i] = (krow * H_ + kblk * 8) * 2;
        const int vrow = 32 * w + 4 * i + (lane >> 4);     // h row
        const int vblk = (lane & 15) ^ (vrow & 7);
        vbyte[i] = (vrow * S_ + vblk * 8) * 2;
    }
    const char* kbase_b = (const char*)(kh + (size_t)(b * S_ + kvbase) * H_);
    const char* vbase_b = (const char*)(vt + (size_t)b * H_ * S_ + kvbase);
    const char* mbase_b = (const char*)(mask + b * S_ + kvbase + lane);

#define ISSUE_TILE(IT)                                                        \
    {                                                                         \
        const char* kb_t = kbase_b + (size_t)(IT) * (128 * H_ * 2);           \
        const char* vb_t = vbase_b + (size_t)(IT) * (128 * 2);                \
        _Pragma("unroll")                                                     \
        for (int i = 0; i < 8; ++i)                                           \
            gload16(kb_t + kbyte[i], &Ks[32 * w + 4 * i][0]);                 \
        _Pragma("unroll")                                                     \
        for (int i = 0; i < 8; ++i)                                           \
            gload16(vb_t + vbyte[i], &Vs[32 * w + 4 * i][0]);                 \
    }

    // Q fragments: lane owns q-row (q0 + 32w + l31); d = 16kt + 8hi + j
    half8 qf[8];
    {
        const _Float16* qp = qh + (size_t)(b * S_ + q0 + 32 * w + l31) * H_ + 8 * hi;
        #pragma unroll
        for (int kt = 0; kt < 8; ++kt) qf[kt] = *(const half8*)(qp + 16 * kt);
    }

    float m_ = -1e30f, l_ = 0.f;
    f32x16 acc2[4];
    #pragma unroll
    for (int hb = 0; hb < 4; ++hb)
        #pragma unroll
        for (int r = 0; r < 16; ++r) acc2[hb][r] = 0.f;

    const auto& KbLo = *(const _Float16(*)[64][128])(&Ks[0][0]);
    const auto& KbHi = *(const _Float16(*)[64][128])(&Ks[64][0]);

    for (int it = 0; it < iters2; ++it) {
        if (it) __syncthreads();   // WAR: all waves done reading previous tile
        ISSUE_TILE(it)
        const int m0 = *(const int*)(mbase_b + (size_t)it * 512);
        const int m1 = *(const int*)(mbase_b + (size_t)it * 512 + 256);
        __syncthreads();           // RAW: drain -> LDS tile valid
        attn_tile32(KbLo, Vs, 0, qf, acc2, m_, l_, m0, lane);
        attn_tile32(KbHi, Vs, 1, qf, acc2, m_, l_, m1, lane);
    }
#undef ISSUE_TILE

    // store unnormalized partials: lane writes its q-row, 64 h-values
    const int qrow = b * S_ + q0 + 32 * w + l31;
    float* op = pout + (size_t)(sp * M_ + qrow) * H_;
    #pragma unroll
    for (int hb = 0; hb < 4; ++hb)
        #pragma unroll
        for (int i = 0; i < 8; ++i) {
            const int h = hb * 32 + 2 * (i & 1) + 8 * (i >> 1) + 4 * hi;
            float2 v2 = make_float2(acc2[hb][2 * i], acc2[hb][2 * i + 1]);
            *(float2*)(op + h) = v2;
        }
    if (hi == 0) {
        pm[sp * M_ + qrow] = m_;
        pl[sp * M_ + qrow] = l_;
    }
}

// ---------------------------------------------------------------------------
// Kernel 3: combine KV-split partials and normalize (exp2 domain).
// ---------------------------------------------------------------------------
__global__ __launch_bounds__(256) void combine_kernel(
    const float* __restrict__ pout, const float* __restrict__ pm,
    const float* __restrict__ pl, float* __restrict__ out, const int nsplit)
{
    const int idx = blockIdx.x * 256 + threadIdx.x;
    const int row = idx >> 7;          // global row
    const int h   = idx & (H_ - 1);
    float M = -1e30f;
    for (int sp = 0; sp < nsplit; ++sp) M = fmaxf(M, pm[sp * M_ + row]);
    float Z = 0.f, o = 0.f;
    for (int sp = 0; sp < nsplit; ++sp) {
        const float wgt = exp2f(pm[sp * M_ + row] - M);
        Z += wgt * pl[sp * M_ + row];
        o += wgt * pout[(size_t)(sp * M_ + row) * H_ + h];
    }
    out[idx] = o / Z;
}

// ---------------------------------------------------------------------------
extern "C" void kernel_launch(void* const* d_in, const int* in_sizes, int n_in,
                              void* d_out, int out_size, void* d_ws, size_t ws_size,
                              hipStream_t stream)
{
    (void)in_sizes; (void)n_in; (void)out_size;
    // setup_inputs order: inputs, Wk, bk, Wq, bq, Wv, bv, padding_mask
    const float* x  = (const float*)d_in[0];
    const float* Wk = (const float*)d_in[1];
    const float* bk = (const float*)d_in[2];
    const float* Wq = (const float*)d_in[3];
    const float* bq = (const float*)d_in[4];
    const float* Wv = (const float*)d_in[5];
    const float* bv = (const float*)d_in[6];
    const int* mask = (const int*)d_in[7];

    char* ws = (char*)d_ws;
    const size_t qkvBytes = (size_t)M_ * H_ * sizeof(_Float16);   // 4 MB each
    _Float16* qh = (_Float16*)ws;
    _Float16* kh = (_Float16*)(ws + qkvBytes);
    _Float16* vt = (_Float16*)(ws + 2 * qkvBytes);                // [B][H][S]
    _Float16* wh = (_Float16*)(ws + 3 * qkvBytes);                // [3][H][D]
    const size_t whBytes = (size_t)3 * H_ * D_ * sizeof(_Float16);
    char* rest = ws + 3 * qkvBytes + whBytes;

    int nsplit = 4;   // proven partials traffic (46 MB); grid 512
    const size_t perSplit = (size_t)M_ * H_ * 4 + 2 * (size_t)M_ * 4;
    while (nsplit > 1 &&
           3 * qkvBytes + whBytes + (size_t)nsplit * perSplit > ws_size) nsplit >>= 1;

    float* pout = (float*)rest;
    float* pm   = (float*)(rest + (size_t)nsplit * M_ * H_ * 4);
    float* pl   = pm + (size_t)nsplit * M_;

    conv_w<<<dim3(3 * H_ * D_ / (256 * 8)), 256, 0, stream>>>(Wq, Wk, Wv, wh);
    proj_kernel<<<dim3(M_ / 64, 3), 256, 0, stream>>>(x, wh, bq, bk, bv, qh, kh, vt);
    attn_kernel<<<dim3(NQT * B_ * nsplit), 256, 0, stream>>>(qh, kh, vt, mask, pout, pm, pl, nsplit);
    combine_kernel<<<dim3(M_ * H_ / 256), 256, 0, stream>>>(pout, pm, pl, (float*)d_out, nsplit);
}

// Round 15
// 104.400 us; speedup vs baseline: 1.9615x; 1.0955x over previous
//
#include <hip/hip_runtime.h>
#include <cmath>

#define B_ 4
#define S_ 4096
#define D_ 1024
#define H_ 128
#define M_ (B_*S_)   // 16384 total rows
#define NQT 32       // S / 128 q-tiles (attn QBLK = 128)

typedef _Float16 half8 __attribute__((ext_vector_type(8)));
typedef _Float16 half4 __attribute__((ext_vector_type(4)));
typedef float f32x4 __attribute__((ext_vector_type(4)));
typedef float f32x16 __attribute__((ext_vector_type(16)));
typedef int i32x4 __attribute__((ext_vector_type(4)));

#define LOG2E 1.44269504088896340f

// async global->LDS, 16B per lane; LDS dest is wave-uniform base + lane*16
__device__ __forceinline__ void gload16(const void* g, void* l) {
    __builtin_amdgcn_global_load_lds(
        (const __attribute__((address_space(1))) unsigned int*)g,
        (__attribute__((address_space(3))) unsigned int*)l,
        16, 0, 0);
}

// ---------------------------------------------------------------------------
// Kernel 0: convert Wq/Wk/Wv (fp32) -> wh fp16 [3][H][D]  (order q,k,v)
// ---------------------------------------------------------------------------
__global__ __launch_bounds__(256) void conv_w(
    const float* __restrict__ Wq, const float* __restrict__ Wk,
    const float* __restrict__ Wv, _Float16* __restrict__ wh)
{
    const int idx  = blockIdx.x * 256 + threadIdx.x;
    const int base = idx * 8;                       // < 3*H*D = 393216
    const int m    = base >> 17;                    // H*D = 131072
    const int off  = base & ((H_ * D_) - 1);
    const float* src = (m == 0 ? Wq : m == 1 ? Wk : Wv) + off;
    const float4 a = ((const float4*)src)[0];
    const float4 c = ((const float4*)src)[1];
    half8 h = { (_Float16)a.x, (_Float16)a.y, (_Float16)a.z, (_Float16)a.w,
                (_Float16)c.x, (_Float16)c.y, (_Float16)c.z, (_Float16)c.w };
    *(half8*)(wh + base) = h;
}

// ---------------------------------------------------------------------------
// Kernel 1: QKV projection.  out = x @ W^T + b  (x fp32, W fp16 via conv_w)
// grid = (M/64, 3): y=0 -> q (scaled by log2e/sqrt(H)), y=1 -> k, y=2 -> v^T
// ---------------------------------------------------------------------------
__global__ __launch_bounds__(256, 3) void proj_kernel(
    const float* __restrict__ x, const _Float16* __restrict__ wh,
    const float* __restrict__ bq, const float* __restrict__ bk,
    const float* __restrict__ bv,
    _Float16* __restrict__ qh, _Float16* __restrict__ kh,
    _Float16* __restrict__ vt)
{
    __shared__ _Float16 Xs[2][64][72];     // +8 pad (reg-staged writes)
    __shared__ _Float16 Ws2[2][128][64];   // content at (r,blk)=G[r][blk^(r&7)]

    const int t = threadIdx.x;
    const int yb = blockIdx.y;
    const float* __restrict__ bias = (yb == 0) ? bq : (yb == 1) ? bk : bv;
    const int m0 = blockIdx.x * 64;
    const int w = t >> 6, lane = t & 63;
    const int lg = lane >> 4, lr = lane & 15;

    f32x4 acc[8];
    #pragma unroll
    for (int i = 0; i < 8; ++i) acc[i] = f32x4{0.f, 0.f, 0.f, 0.f};

    const int xrow = t >> 2, xc = (t & 3) * 16;   // X tile: 64x64, 16 f/thread
    const float* xbase = x + (size_t)(m0 + xrow) * D_ + xc;

    // W staging offsets (V-style swizzle): 4 gloads cover rows 32w..32w+32
    int wbyte[4];
    #pragma unroll
    for (int i = 0; i < 4; ++i) {
        const int wrow = 32 * w + 8 * i + (lane >> 3);
        const int wblk = (lane & 7) ^ (lane >> 3);
        wbyte[i] = (wrow * D_ + wblk * 8) * 2;
    }
    const char* whb = (const char*)(wh + (size_t)yb * H_ * D_);

    float4 xfA[4], xfB[4];

#define WISSUE(KT, BUF)                                                       \
    {                                                                         \
        const char* wsrc = whb + (KT) * (64 * 2);                             \
        _Pragma("unroll")                                                     \
        for (int i = 0; i < 4; ++i)                                           \
            gload16(wsrc + wbyte[i], &Ws2[BUF][32 * w + 8 * i][0]);           \
    }
#define XISSUE(KT, XS)                                                        \
    {                                                                         \
        const float4* xs_ = (const float4*)(xbase + (KT) * 64);               \
        _Pragma("unroll") for (int i = 0; i < 4; ++i) XS[i] = xs_[i];         \
    }
#define XWRITE(XS, BUF)                                                       \
    {                                                                         \
        _Pragma("unroll") for (int i = 0; i < 4; ++i) {                       \
            half4 h = { (_Float16)XS[i].x, (_Float16)XS[i].y,                 \
                        (_Float16)XS[i].z, (_Float16)XS[i].w };               \
            *(half4*)&Xs[BUF][xrow][xc + 4 * i] = h;                          \
        }                                                                     \
    }
#define PMFMA(BUF)                                                            \
    {                                                                         \
        _Pragma("unroll") for (int kk = 0; kk < 2; ++kk) {                    \
            half8 a = *(const half8*)&Xs[BUF][w * 16 + lr][kk * 32 + 8 * lg]; \
            _Pragma("unroll") for (int ni = 0; ni < 8; ++ni) {                \
                half8 bfr = *(const half8*)&Ws2[BUF][ni * 16 + lr]            \
                                [((4 * kk + lg) ^ (lr & 7)) * 8];             \
                acc[ni] = __builtin_amdgcn_mfma_f32_16x16x32_f16(a, bfr, acc[ni], 0, 0, 0); \
            }                                                                 \
        }                                                                     \
    }

    WISSUE(0, 0)
    XISSUE(0, xfA)
    XISSUE(1, xfB)
    XWRITE(xfA, 0)
    __syncthreads();   // drains W0 gloads + X0 writes

    for (int kt = 0; kt < 16; kt += 2) {
        // ---- even tile kt (buf 0) ----
        WISSUE(kt + 1, 1)
        if (kt + 2 < 16) XISSUE(kt + 2, xfA)
        PMFMA(0)
        XWRITE(xfB, 1)
        __syncthreads();
        // ---- odd tile kt+1 (buf 1) ----
        if (kt + 2 < 16) WISSUE(kt + 2, 0)
        if (kt + 3 < 16) XISSUE(kt + 3, xfB)
        PMFMA(1)
        if (kt + 2 < 16) XWRITE(xfA, 0)
        __syncthreads();
    }
#undef WISSUE
#undef XISSUE
#undef XWRITE
#undef PMFMA

    // q scale folds 1/sqrt(128) AND log2(e) (softmax runs in exp2 domain)
    const float qscale = 0.08838834764831845f * LOG2E;
    const int rowb = m0 + w * 16 + lg * 4;   // C/D: row = 4*(lane>>4)+r, col = ni*16+lr
    #pragma unroll
    for (int ni = 0; ni < 8; ++ni) {
        const int col = ni * 16 + lr;
        const float bval = bias[col];
        if (yb == 0) {
            #pragma unroll
            for (int r = 0; r < 4; ++r)
                qh[(size_t)(rowb + r) * H_ + col] = (_Float16)((acc[ni][r] + bval) * qscale);
        } else if (yb == 1) {
            #pragma unroll
            for (int r = 0; r < 4; ++r)
                kh[(size_t)(rowb + r) * H_ + col] = (_Float16)(acc[ni][r] + bval);
        } else {
            const int bb = rowb >> 12, s0 = rowb & (S_ - 1);
            half4 h;
            #pragma unroll
            for (int r = 0; r < 4; ++r) h[r] = (_Float16)(acc[ni][r] + bval);
            *(half4*)&vt[(size_t)bb * H_ * S_ + (size_t)col * S_ + s0] = h;
        }
    }
}

// ---------------------------------------------------------------------------
// Kernel 2: flash attention, 32x32x16 MFMA core — best-measured variant
// (benched Round 9: attn ~78 us). Swapped operands (lane owns one q-row),
// exp2 softmax, defer-max, shfl_xor P-exchange, pre-swizzled-source gload16,
// ping-pong double buffer, ONE __syncthreads per tile.
// C/D map (m74/m101): col = lane&31, row = (r&3) + 8*(r>>2) + 4*(lane>>5).
// ---------------------------------------------------------------------------
__device__ __forceinline__ void attn_tile32(
    const _Float16 (&Kb)[64][128], const _Float16 (&Vb)[128][64],
    const half8 (&qf)[8], f32x16 (&acc2)[4], float& m_, float& l_,
    int muse, int lane)
{
    const unsigned long long bz = __ballot(muse == 0);
    const int l31 = lane & 31, l7 = lane & 7, hi = lane >> 5;

    // S^T = K Q^T : sf[nb][r] = S'[kv = 32nb + (r&3)+8*(r>>2)+4hi][q = l31]
    f32x16 sf[2];
    #pragma unroll
    for (int nb = 0; nb < 2; ++nb)
        #pragma unroll
        for (int r = 0; r < 16; ++r) sf[nb][r] = 0.f;
    #pragma unroll
    for (int kt = 0; kt < 8; ++kt) {
        #pragma unroll
        for (int nb = 0; nb < 2; ++nb) {
            half8 kb = *(const half8*)&Kb[nb * 32 + l31][((2 * kt + hi) ^ l7) * 8];
            sf[nb] = __builtin_amdgcn_mfma_f32_32x32x16_f16(kb, qf[kt], sf[nb], 0, 0, 0);
        }
    }
    if (bz) {   // padding mask (reference: where(mask==0, -1e9))
        #pragma unroll
        for (int nb = 0; nb < 2; ++nb)
            #pragma unroll
            for (int r = 0; r < 16; ++r) {
                const int kv = nb * 32 + (r & 3) + 8 * (r >> 2) + 4 * hi;
                if ((bz >> kv) & 1ull) sf[nb][r] = -3e9f;
            }
    }
    // online softmax in exp2 domain: one q-row per lane, ONE shuffle
    float tmax = sf[0][0];
    #pragma unroll
    for (int nb = 0; nb < 2; ++nb)
        #pragma unroll
        for (int r = 0; r < 16; ++r) tmax = fmaxf(tmax, sf[nb][r]);
    tmax = fmaxf(tmax, __shfl_xor(tmax, 32));
    if (!__all(tmax <= m_ + 8.f)) {   // defer-max: skip rescale when safe
        const float mn  = fmaxf(m_, tmax);
        const float scl = exp2f(m_ - mn);
        m_ = mn; l_ *= scl;
        #pragma unroll
        for (int hb = 0; hb < 4; ++hb) acc2[hb] *= scl;
    }
    float rsum = 0.f;
    #pragma unroll
    for (int nb = 0; nb < 2; ++nb)
        #pragma unroll
        for (int r = 0; r < 16; ++r) {
            const float p = exp2f(sf[nb][r] - m_);
            sf[nb][r] = p;
            rsum += p;
        }
    rsum += __shfl_xor(rsum, 32);
    l_ += rsum;

    // pack P pairs: pkw[nb][i] holds kv = 32nb + 8*(i>>1) + 4hi + 2*(i&1), +1
    int pkw[2][8];
    #pragma unroll
    for (int nb = 0; nb < 2; ++nb)
        #pragma unroll
        for (int i = 0; i < 8; ++i) {
            auto h2 = __builtin_amdgcn_cvt_pkrtz(sf[nb][2 * i], sf[nb][2 * i + 1]);
            pkw[nb][i] = __builtin_bit_cast(int, h2);
        }
    // exchange across lane halves (direction-unambiguous shfl_xor):
    // lo lanes keep w0,w1 and receive other-half's w0,w1 as w2,w3;
    // hi lanes keep w2,w3 and receive other-half's w2,w3 as w0,w1.
    #pragma unroll
    for (int nb = 0; nb < 2; ++nb)
        #pragma unroll
        for (int hf = 0; hf < 2; ++hf) {
            const int i0 = hf * 4;
            const int sA = hi ? pkw[nb][i0 + 0] : pkw[nb][i0 + 2];
            const int sB = hi ? pkw[nb][i0 + 1] : pkw[nb][i0 + 3];
            const int rA = __shfl_xor(sA, 32);   // lo<-hi's w0 ; hi<-lo's w2
            const int rB = __shfl_xor(sB, 32);   // lo<-hi's w1 ; hi<-lo's w3
            const int n0 = hi ? rA : pkw[nb][i0 + 0];
            const int n1 = hi ? rB : pkw[nb][i0 + 1];
            const int n2 = hi ? pkw[nb][i0 + 2] : rA;
            const int n3 = hi ? pkw[nb][i0 + 3] : rB;
            pkw[nb][i0 + 0] = n0; pkw[nb][i0 + 1] = n1;
            pkw[nb][i0 + 2] = n2; pkw[nb][i0 + 3] = n3;
        }
    // O^T += V^T P^T : acc2[hb][r] = O[q=l31][h = 32hb + (r&3)+8*(r>>2)+4hi]
    #pragma unroll
    for (int s = 0; s < 4; ++s) {
        const int nb = s >> 1, hf = s & 1;
        const half8 pb = __builtin_bit_cast(half8,
            i32x4{ pkw[nb][hf * 4 + 0], pkw[nb][hf * 4 + 1],
                   pkw[nb][hf * 4 + 2], pkw[nb][hf * 4 + 3] });
        #pragma unroll
        for (int hb = 0; hb < 4; ++hb) {
            half8 vb = *(const half8*)&Vb[hb * 32 + l31][((2 * s + hi) ^ l7) * 8];
            acc2[hb] = __builtin_amdgcn_mfma_f32_32x32x16_f16(vb, pb, acc2[hb], 0, 0, 0);
        }
    }
}

__global__ __launch_bounds__(256, 2) void attn_kernel(
    const _Float16* __restrict__ qh, const _Float16* __restrict__ kh,
    const _Float16* __restrict__ vt, const int* __restrict__ mask,
    float* __restrict__ pout, float* __restrict__ pm, float* __restrict__ pl,
    const int nsplit)
{
    __shared__ _Float16 Ks[2][64][128];   // [buf][kv][d]; content swizzled
    __shared__ _Float16 Vs[2][128][64];   // [buf][h][kv]

    const int t = threadIdx.x;
    const int id = blockIdx.x;
    // L2-locality swizzle: each XCD owns ncombo/8 (b,split) combos.
    int qt, sp, b;
    const int ncombo = B_ * nsplit;
    if ((ncombo & 7) == 0) {
        const int per_xcd = ncombo >> 3;
        const int j = id >> 3;
        qt = j & (NQT - 1);
        const int combo = (id & 7) * per_xcd + (j >> 5);   // log2(NQT)=5
        sp = combo % nsplit; b = combo / nsplit;
    } else {
        qt = id & (NQT - 1);
        const int rest = id >> 5;
        sp = rest % nsplit; b = rest / nsplit;
    }
    const int q0 = qt * 128;
    const int w = t >> 6, lane = t & 63;
    const int l31 = lane & 31, hi = lane >> 5;
    const int kvlen  = S_ / nsplit;
    const int iters  = kvlen >> 6;
    const int kvbase = sp * kvlen;

    // per-lane byte offsets of the SWIZZLED global source (loop-invariant)
    int kbyte[4], vbyte[4];
    #pragma unroll
    for (int i = 0; i < 4; ++i) {
        const int krow = 16 * w + 4 * i + (lane >> 4);
        const int kblk = (lane & 15) ^ (krow & 7);
        kbyte[i] = (krow * H_ + kblk * 8) * 2;
        const int vrow = 32 * w + 8 * i + (lane >> 3);
        const int vblk = (lane & 7) ^ (lane >> 3);   // vrow&7 == lane>>3
        vbyte[i] = (vrow * S_ + vblk * 8) * 2;
    }
    const char* kbase_b = (const char*)(kh + (size_t)(b * S_ + kvbase) * H_);
    const char* vbase_b = (const char*)(vt + (size_t)b * H_ * S_ + kvbase);
    const char* mbase_b = (const char*)(mask + b * S_ + kvbase + lane);

#define ISSUE_TILE(IT, NB)                                                    \
    {                                                                         \
        const char* kb_t = kbase_b + (size_t)(IT) * (64 * H_ * 2);            \
        const char* vb_t = vbase_b + (size_t)(IT) * (64 * 2);                 \
        _Pragma("unroll")                                                     \
        for (int i = 0; i < 4; ++i)                                           \
            gload16(kb_t + kbyte[i], &Ks[NB][16 * w + 4 * i][0]);             \
        _Pragma("unroll")                                                     \
        for (int i = 0; i < 4; ++i)                                           \
            gload16(vb_t + vbyte[i], &Vs[NB][32 * w + 8 * i][0]);             \
    }

    // Q fragments: lane owns q-row (q0 + 32w + l31); d = 16kt + 8hi + j
    half8 qf[8];
    {
        const _Float16* qp = qh + (size_t)(b * S_ + q0 + 32 * w + l31) * H_ + 8 * hi;
        #pragma unroll
        for (int kt = 0; kt < 8; ++kt) qf[kt] = *(const half8*)(qp + 16 * kt);
    }

    float m_ = -1e30f, l_ = 0.f;
    f32x16 acc2[4];
    #pragma unroll
    for (int hb = 0; hb < 4; ++hb)
        #pragma unroll
        for (int r = 0; r < 16; ++r) acc2[hb][r] = 0.f;

    ISSUE_TILE(0, 0)
    int mA = *(const int*)mbase_b;
    int mB = 0;
    __syncthreads();   // tile 0 staged

    for (int it = 0; it < iters; it += 2) {
        // ---- tile it (buf 0); prefetch it+1 flies during this compute ----
        if (it + 1 < iters) {
            ISSUE_TILE(it + 1, 1)
            mB = *(const int*)(mbase_b + (size_t)(it + 1) * 256);
        }
        attn_tile32(Ks[0], Vs[0], qf, acc2, m_, l_, mA, lane);
        __syncthreads();
        // ---- tile it+1 (buf 1); prefetch it+2 flies during this compute ----
        if (it + 2 < iters) {
            ISSUE_TILE(it + 2, 0)
            mA = *(const int*)(mbase_b + (size_t)(it + 2) * 256);
        }
        if (it + 1 < iters)
            attn_tile32(Ks[1], Vs[1], qf, acc2, m_, l_, mB, lane);
        __syncthreads();
    }
#undef ISSUE_TILE

    // store unnormalized partials: lane writes its q-row, 64 h-values
    const int qrow = b * S_ + q0 + 32 * w + l31;
    float* op = pout + (size_t)(sp * M_ + qrow) * H_;
    #pragma unroll
    for (int hb = 0; hb < 4; ++hb)
        #pragma unroll
        for (int i = 0; i < 8; ++i) {
            const int h = hb * 32 + 2 * (i & 1) + 8 * (i >> 1) + 4 * hi;
            float2 v2 = make_float2(acc2[hb][2 * i], acc2[hb][2 * i + 1]);
            *(float2*)(op + h) = v2;
        }
    if (hi == 0) {
        pm[sp * M_ + qrow] = m_;
        pl[sp * M_ + qrow] = l_;
    }
}

// ---------------------------------------------------------------------------
// Kernel 3: combine KV-split partials and normalize (exp2 domain).
// Vectorized: each thread handles 4 h-values (f32x4 loads/stores);
// pm/pl loads amortized 4x.
// ---------------------------------------------------------------------------
__global__ __launch_bounds__(256) void combine_kernel(
    const float* __restrict__ pout, const float* __restrict__ pm,
    const float* __restrict__ pl, float* __restrict__ out, const int nsplit)
{
    const int idx = blockIdx.x * 256 + threadIdx.x;   // < M_*H_/4
    const int row = idx >> 5;          // global row (32 f32x4 per row)
    const int c4  = (idx & 31) * 4;
    float M = -1e30f;
    for (int sp = 0; sp < nsplit; ++sp) M = fmaxf(M, pm[sp * M_ + row]);
    float Z = 0.f;
    f32x4 o = f32x4{0.f, 0.f, 0.f, 0.f};
    for (int sp = 0; sp < nsplit; ++sp) {
        const float wgt = exp2f(pm[sp * M_ + row] - M);
        Z += wgt * pl[sp * M_ + row];
        const f32x4 p = *(const f32x4*)&pout[(size_t)(sp * M_ + row) * H_ + c4];
        o += wgt * p;
    }
    const float inv = 1.f / Z;
    *(f32x4*)&out[(size_t)row * H_ + c4] = o * inv;
}

// ---------------------------------------------------------------------------
extern "C" void kernel_launch(void* const* d_in, const int* in_sizes, int n_in,
                              void* d_out, int out_size, void* d_ws, size_t ws_size,
                              hipStream_t stream)
{
    (void)in_sizes; (void)n_in; (void)out_size;
    // setup_inputs order: inputs, Wk, bk, Wq, bq, Wv, bv, padding_mask
    const float* x  = (const float*)d_in[0];
    const float* Wk = (const float*)d_in[1];
    const float* bk = (const float*)d_in[2];
    const float* Wq = (const float*)d_in[3];
    const float* bq = (const float*)d_in[4];
    const float* Wv = (const float*)d_in[5];
    const float* bv = (const float*)d_in[6];
    const int* mask = (const int*)d_in[7];

    char* ws = (char*)d_ws;
    const size_t qkvBytes = (size_t)M_ * H_ * sizeof(_Float16);   // 4 MB each
    _Float16* qh = (_Float16*)ws;
    _Float16* kh = (_Float16*)(ws + qkvBytes);
    _Float16* vt = (_Float16*)(ws + 2 * qkvBytes);                // [B][H][S]
    _Float16* wh = (_Float16*)(ws + 3 * qkvBytes);                // [3][H][D]
    const size_t whBytes = (size_t)3 * H_ * D_ * sizeof(_Float16);
    char* rest = ws + 3 * qkvBytes + whBytes;

    int nsplit = 4;   // best-measured: 512 blocks = 2/CU, 46 MB partials
    const size_t perSplit = (size_t)M_ * H_ * 4 + 2 * (size_t)M_ * 4;
    while (nsplit > 1 &&
           3 * qkvBytes + whBytes + (size_t)nsplit * perSplit > ws_size) nsplit >>= 1;

    float* pout = (float*)rest;
    float* pm   = (float*)(rest + (size_t)nsplit * M_ * H_ * 4);
    float* pl   = pm + (size_t)nsplit * M_;

    conv_w<<<dim3(3 * H_ * D_ / (256 * 8)), 256, 0, stream>>>(Wq, Wk, Wv, wh);
    proj_kernel<<<dim3(M_ / 64, 3), 256, 0, stream>>>(x, wh, bq, bk, bv, qh, kh, vt);
    attn_kernel<<<dim3(NQT * B_ * nsplit), 256, 0, stream>>>(qh, kh, vt, mask, pout, pm, pl, nsplit);
    combine_kernel<<<dim3(M_ * H_ / (256 * 4)), 256, 0, stream>>>(pout, pm, pl, (float*)d_out, nsplit);
}

// Round 16
// 103.212 us; speedup vs baseline: 1.9841x; 1.0115x over previous
//
#include <hip/hip_runtime.h>
#include <cmath>

#define B_ 4
#define S_ 4096
#define D_ 1024
#define H_ 128
#define M_ (B_*S_)   // 16384 total rows
#define NQT 32       // S / 128 q-tiles (attn QBLK = 128)

typedef _Float16 half8 __attribute__((ext_vector_type(8)));
typedef _Float16 half4 __attribute__((ext_vector_type(4)));
typedef float f32x4 __attribute__((ext_vector_type(4)));
typedef float f32x16 __attribute__((ext_vector_type(16)));
typedef int i32x4 __attribute__((ext_vector_type(4)));

#define LOG2E 1.44269504088896340f

// async global->LDS, 16B per lane; LDS dest is wave-uniform base + lane*16
__device__ __forceinline__ void gload16(const void* g, void* l) {
    __builtin_amdgcn_global_load_lds(
        (const __attribute__((address_space(1))) unsigned int*)g,
        (__attribute__((address_space(3))) unsigned int*)l,
        16, 0, 0);
}

// ---------------------------------------------------------------------------
// Kernel 0: convert Wq/Wk/Wv (fp32) -> wh fp16 [3][H][D]  (order q,k,v)
// ---------------------------------------------------------------------------
__global__ __launch_bounds__(256) void conv_w(
    const float* __restrict__ Wq, const float* __restrict__ Wk,
    const float* __restrict__ Wv, _Float16* __restrict__ wh)
{
    const int idx  = blockIdx.x * 256 + threadIdx.x;
    const int base = idx * 8;                       // < 3*H*D = 393216
    const int m    = base >> 17;                    // H*D = 131072
    const int off  = base & ((H_ * D_) - 1);
    const float* src = (m == 0 ? Wq : m == 1 ? Wk : Wv) + off;
    const float4 a = ((const float4*)src)[0];
    const float4 c = ((const float4*)src)[1];
    half8 h = { (_Float16)a.x, (_Float16)a.y, (_Float16)a.z, (_Float16)a.w,
                (_Float16)c.x, (_Float16)c.y, (_Float16)c.z, (_Float16)c.w };
    *(half8*)(wh + base) = h;
}

// ---------------------------------------------------------------------------
// Kernel 1: QKV projection.  out = x @ W^T + b  (x fp32, W fp16 via conv_w)
// grid = (M/64, 3): y=0 -> q (scaled by log2e/sqrt(H)), y=1 -> k, y=2 -> v^T
// This round: W SINGLE-buffered (16 KB) -> LDS 34.4 KB -> 4 blocks/CU
// (was 3); cross-block overlap hides the per-kt W drain (W is L1/L2-hot).
// X keeps the proven 2-deep register pipeline into a double-buffered Xs.
// ---------------------------------------------------------------------------
__global__ __launch_bounds__(256, 4) void proj_kernel(
    const float* __restrict__ x, const _Float16* __restrict__ wh,
    const float* __restrict__ bq, const float* __restrict__ bk,
    const float* __restrict__ bv,
    _Float16* __restrict__ qh, _Float16* __restrict__ kh,
    _Float16* __restrict__ vt)
{
    __shared__ _Float16 Xs[2][64][72];   // +8 pad (reg-staged writes), 18.4 KB
    __shared__ _Float16 Ws2[128][64];    // single buffer, 16 KB;
                                         // content at (r,blk)=G[r][blk^(r&7)]

    const int t = threadIdx.x;
    const int yb = blockIdx.y;
    const float* __restrict__ bias = (yb == 0) ? bq : (yb == 1) ? bk : bv;
    const int m0 = blockIdx.x * 64;
    const int w = t >> 6, lane = t & 63;
    const int lg = lane >> 4, lr = lane & 15;

    f32x4 acc[8];
    #pragma unroll
    for (int i = 0; i < 8; ++i) acc[i] = f32x4{0.f, 0.f, 0.f, 0.f};

    const int xrow = t >> 2, xc = (t & 3) * 16;   // X tile: 64x64, 16 f/thread
    const float* xbase = x + (size_t)(m0 + xrow) * D_ + xc;

    // W staging offsets (V-style swizzle): 4 gloads cover rows 32w..32w+32
    int wbyte[4];
    #pragma unroll
    for (int i = 0; i < 4; ++i) {
        const int wrow = 32 * w + 8 * i + (lane >> 3);
        const int wblk = (lane & 7) ^ (lane >> 3);
        wbyte[i] = (wrow * D_ + wblk * 8) * 2;
    }
    const char* whb = (const char*)(wh + (size_t)yb * H_ * D_);

    float4 xfA[4], xfB[4];

#define WISSUE(KT)                                                            \
    {                                                                         \
        const char* wsrc = whb + (KT) * (64 * 2);                             \
        _Pragma("unroll")                                                     \
        for (int i = 0; i < 4; ++i)                                           \
            gload16(wsrc + wbyte[i], &Ws2[32 * w + 8 * i][0]);                \
    }
#define XISSUE(KT, XS)                                                        \
    {                                                                         \
        const float4* xs_ = (const float4*)(xbase + (KT) * 64);               \
        _Pragma("unroll") for (int i = 0; i < 4; ++i) XS[i] = xs_[i];         \
    }
#define XWRITE(XS, BUF)                                                       \
    {                                                                         \
        _Pragma("unroll") for (int i = 0; i < 4; ++i) {                       \
            half4 h = { (_Float16)XS[i].x, (_Float16)XS[i].y,                 \
                        (_Float16)XS[i].z, (_Float16)XS[i].w };               \
            *(half4*)&Xs[BUF][xrow][xc + 4 * i] = h;                          \
        }                                                                     \
    }
#define PMFMA(BUF)                                                            \
    {                                                                         \
        _Pragma("unroll") for (int kk = 0; kk < 2; ++kk) {                    \
            half8 a = *(const half8*)&Xs[BUF][w * 16 + lr][kk * 32 + 8 * lg]; \
            _Pragma("unroll") for (int ni = 0; ni < 8; ++ni) {                \
                half8 bfr = *(const half8*)&Ws2[ni * 16 + lr]                 \
                                [((4 * kk + lg) ^ (lr & 7)) * 8];             \
                acc[ni] = __builtin_amdgcn_mfma_f32_16x16x32_f16(a, bfr, acc[ni], 0, 0, 0); \
            }                                                                 \
        }                                                                     \
    }

    // prologue: xfA=X(0), xfB=X(1); X(0)->buf0; W(0) staged.
    XISSUE(0, xfA)
    XISSUE(1, xfB)
    XWRITE(xfA, 0)
    WISSUE(0)
    __syncthreads();   // drains W0 gloads + X0 writes

    for (int kt = 0; kt < 16; kt += 2) {
        // ---- even tile kt: X in buf0, regs xfB hold X(kt+1) ----
        PMFMA(0)
        XWRITE(xfB, 1)                        // X(kt+1) -> buf1
        if (kt + 2 < 16) XISSUE(kt + 2, xfA)  // refill xfA with X(kt+2)
        __syncthreads();                      // all waves done with Ws(kt)
        WISSUE(kt + 1)                        // overwrite Ws with W(kt+1)
        __syncthreads();                      // W(kt+1) landed (drain)
        // ---- odd tile kt+1: X in buf1, regs xfA hold X(kt+2) ----
        PMFMA(1)
        if (kt + 2 < 16) {
            XWRITE(xfA, 0)                    // X(kt+2) -> buf0
            if (kt + 3 < 16) XISSUE(kt + 3, xfB)
            __syncthreads();                  // all waves done with Ws(kt+1)
            WISSUE(kt + 2)
            __syncthreads();                  // W(kt+2) landed
        }
    }
#undef WISSUE
#undef XISSUE
#undef XWRITE
#undef PMFMA

    // q scale folds 1/sqrt(128) AND log2(e) (softmax runs in exp2 domain)
    const float qscale = 0.08838834764831845f * LOG2E;
    const int rowb = m0 + w * 16 + lg * 4;   // C/D: row = 4*(lane>>4)+r, col = ni*16+lr
    #pragma unroll
    for (int ni = 0; ni < 8; ++ni) {
        const int col = ni * 16 + lr;
        const float bval = bias[col];
        if (yb == 0) {
            #pragma unroll
            for (int r = 0; r < 4; ++r)
                qh[(size_t)(rowb + r) * H_ + col] = (_Float16)((acc[ni][r] + bval) * qscale);
        } else if (yb == 1) {
            #pragma unroll
            for (int r = 0; r < 4; ++r)
                kh[(size_t)(rowb + r) * H_ + col] = (_Float16)(acc[ni][r] + bval);
        } else {
            const int bb = rowb >> 12, s0 = rowb & (S_ - 1);
            half4 h;
            #pragma unroll
            for (int r = 0; r < 4; ++r) h[r] = (_Float16)(acc[ni][r] + bval);
            *(half4*)&vt[(size_t)bb * H_ * S_ + (size_t)col * S_ + s0] = h;
        }
    }
}

// ---------------------------------------------------------------------------
// Kernel 2: flash attention, 32x32x16 MFMA core — best-measured variant
// (R9/R15: attn ~78 us). Swapped operands (lane owns one q-row), exp2
// softmax, defer-max, shfl_xor P-exchange, pre-swizzled-source gload16,
// ping-pong double buffer, ONE __syncthreads per tile. UNCHANGED from R15.
// C/D map (m74/m101): col = lane&31, row = (r&3) + 8*(r>>2) + 4*(lane>>5).
// ---------------------------------------------------------------------------
__device__ __forceinline__ void attn_tile32(
    const _Float16 (&Kb)[64][128], const _Float16 (&Vb)[128][64],
    const half8 (&qf)[8], f32x16 (&acc2)[4], float& m_, float& l_,
    int muse, int lane)
{
    const unsigned long long bz = __ballot(muse == 0);
    const int l31 = lane & 31, l7 = lane & 7, hi = lane >> 5;

    // S^T = K Q^T : sf[nb][r] = S'[kv = 32nb + (r&3)+8*(r>>2)+4hi][q = l31]
    f32x16 sf[2];
    #pragma unroll
    for (int nb = 0; nb < 2; ++nb)
        #pragma unroll
        for (int r = 0; r < 16; ++r) sf[nb][r] = 0.f;
    #pragma unroll
    for (int kt = 0; kt < 8; ++kt) {
        #pragma unroll
        for (int nb = 0; nb < 2; ++nb) {
            half8 kb = *(const half8*)&Kb[nb * 32 + l31][((2 * kt + hi) ^ l7) * 8];
            sf[nb] = __builtin_amdgcn_mfma_f32_32x32x16_f16(kb, qf[kt], sf[nb], 0, 0, 0);
        }
    }
    if (bz) {   // padding mask (reference: where(mask==0, -1e9))
        #pragma unroll
        for (int nb = 0; nb < 2; ++nb)
            #pragma unroll
            for (int r = 0; r < 16; ++r) {
                const int kv = nb * 32 + (r & 3) + 8 * (r >> 2) + 4 * hi;
                if ((bz >> kv) & 1ull) sf[nb][r] = -3e9f;
            }
    }
    // online softmax in exp2 domain: one q-row per lane, ONE shuffle
    float tmax = sf[0][0];
    #pragma unroll
    for (int nb = 0; nb < 2; ++nb)
        #pragma unroll
        for (int r = 0; r < 16; ++r) tmax = fmaxf(tmax, sf[nb][r]);
    tmax = fmaxf(tmax, __shfl_xor(tmax, 32));
    if (!__all(tmax <= m_ + 8.f)) {   // defer-max: skip rescale when safe
        const float mn  = fmaxf(m_, tmax);
        const float scl = exp2f(m_ - mn);
        m_ = mn; l_ *= scl;
        #pragma unroll
        for (int hb = 0; hb < 4; ++hb) acc2[hb] *= scl;
    }
    float rsum = 0.f;
    #pragma unroll
    for (int nb = 0; nb < 2; ++nb)
        #pragma unroll
        for (int r = 0; r < 16; ++r) {
            const float p = exp2f(sf[nb][r] - m_);
            sf[nb][r] = p;
            rsum += p;
        }
    rsum += __shfl_xor(rsum, 32);
    l_ += rsum;

    // pack P pairs: pkw[nb][i] holds kv = 32nb + 8*(i>>1) + 4hi + 2*(i&1), +1
    int pkw[2][8];
    #pragma unroll
    for (int nb = 0; nb < 2; ++nb)
        #pragma unroll
        for (int i = 0; i < 8; ++i) {
            auto h2 = __builtin_amdgcn_cvt_pkrtz(sf[nb][2 * i], sf[nb][2 * i + 1]);
            pkw[nb][i] = __builtin_bit_cast(int, h2);
        }
    // exchange across lane halves (direction-unambiguous shfl_xor):
    // lo lanes keep w0,w1 and receive other-half's w0,w1 as w2,w3;
    // hi lanes keep w2,w3 and receive other-half's w2,w3 as w0,w1.
    #pragma unroll
    for (int nb = 0; nb < 2; ++nb)
        #pragma unroll
        for (int hf = 0; hf < 2; ++hf) {
            const int i0 = hf * 4;
            const int sA = hi ? pkw[nb][i0 + 0] : pkw[nb][i0 + 2];
            const int sB = hi ? pkw[nb][i0 + 1] : pkw[nb][i0 + 3];
            const int rA = __shfl_xor(sA, 32);   // lo<-hi's w0 ; hi<-lo's w2
            const int rB = __shfl_xor(sB, 32);   // lo<-hi's w1 ; hi<-lo's w3
            const int n0 = hi ? rA : pkw[nb][i0 + 0];
            const int n1 = hi ? rB : pkw[nb][i0 + 1];
            const int n2 = hi ? pkw[nb][i0 + 2] : rA;
            const int n3 = hi ? pkw[nb][i0 + 3] : rB;
            pkw[nb][i0 + 0] = n0; pkw[nb][i0 + 1] = n1;
            pkw[nb][i0 + 2] = n2; pkw[nb][i0 + 3] = n3;
        }
    // O^T += V^T P^T : acc2[hb][r] = O[q=l31][h = 32hb + (r&3)+8*(r>>2)+4hi]
    #pragma unroll
    for (int s = 0; s < 4; ++s) {
        const int nb = s >> 1, hf = s & 1;
        const half8 pb = __builtin_bit_cast(half8,
            i32x4{ pkw[nb][hf * 4 + 0], pkw[nb][hf * 4 + 1],
                   pkw[nb][hf * 4 + 2], pkw[nb][hf * 4 + 3] });
        #pragma unroll
        for (int hb = 0; hb < 4; ++hb) {
            half8 vb = *(const half8*)&Vb[hb * 32 + l31][((2 * s + hi) ^ l7) * 8];
            acc2[hb] = __builtin_amdgcn_mfma_f32_32x32x16_f16(vb, pb, acc2[hb], 0, 0, 0);
        }
    }
}

__global__ __launch_bounds__(256, 2) void attn_kernel(
    const _Float16* __restrict__ qh, const _Float16* __restrict__ kh,
    const _Float16* __restrict__ vt, const int* __restrict__ mask,
    float* __restrict__ pout, float* __restrict__ pm, float* __restrict__ pl,
    const int nsplit)
{
    __shared__ _Float16 Ks[2][64][128];   // [buf][kv][d]; content swizzled
    __shared__ _Float16 Vs[2][128][64];   // [buf][h][kv]

    const int t = threadIdx.x;
    const int id = blockIdx.x;
    // L2-locality swizzle: each XCD owns ncombo/8 (b,split) combos.
    int qt, sp, b;
    const int ncombo = B_ * nsplit;
    if ((ncombo & 7) == 0) {
        const int per_xcd = ncombo >> 3;
        const int j = id >> 3;
        qt = j & (NQT - 1);
        const int combo = (id & 7) * per_xcd + (j >> 5);   // log2(NQT)=5
        sp = combo % nsplit; b = combo / nsplit;
    } else {
        qt = id & (NQT - 1);
        const int rest = id >> 5;
        sp = rest % nsplit; b = rest / nsplit;
    }
    const int q0 = qt * 128;
    const int w = t >> 6, lane = t & 63;
    const int l31 = lane & 31, hi = lane >> 5;
    const int kvlen  = S_ / nsplit;
    const int iters  = kvlen >> 6;
    const int kvbase = sp * kvlen;

    // per-lane byte offsets of the SWIZZLED global source (loop-invariant)
    int kbyte[4], vbyte[4];
    #pragma unroll
    for (int i = 0; i < 4; ++i) {
        const int krow = 16 * w + 4 * i + (lane >> 4);
        const int kblk = (lane & 15) ^ (krow & 7);
        kbyte[i] = (krow * H_ + kblk * 8) * 2;
        const int vrow = 32 * w + 8 * i + (lane >> 3);
        const int vblk = (lane & 7) ^ (lane >> 3);   // vrow&7 == lane>>3
        vbyte[i] = (vrow * S_ + vblk * 8) * 2;
    }
    const char* kbase_b = (const char*)(kh + (size_t)(b * S_ + kvbase) * H_);
    const char* vbase_b = (const char*)(vt + (size_t)b * H_ * S_ + kvbase);
    const char* mbase_b = (const char*)(mask + b * S_ + kvbase + lane);

#define ISSUE_TILE(IT, NB)                                                    \
    {                                                                         \
        const char* kb_t = kbase_b + (size_t)(IT) * (64 * H_ * 2);            \
        const char* vb_t = vbase_b + (size_t)(IT) * (64 * 2);                 \
        _Pragma("unroll")                                                     \
        for (int i = 0; i < 4; ++i)                                           \
            gload16(kb_t + kbyte[i], &Ks[NB][16 * w + 4 * i][0]);             \
        _Pragma("unroll")                                                     \
        for (int i = 0; i < 4; ++i)                                           \
            gload16(vb_t + vbyte[i], &Vs[NB][32 * w + 8 * i][0]);             \
    }

    // Q fragments: lane owns q-row (q0 + 32w + l31); d = 16kt + 8hi + j
    half8 qf[8];
    {
        const _Float16* qp = qh + (size_t)(b * S_ + q0 + 32 * w + l31) * H_ + 8 * hi;
        #pragma unroll
        for (int kt = 0; kt < 8; ++kt) qf[kt] = *(const half8*)(qp + 16 * kt);
    }

    float m_ = -1e30f, l_ = 0.f;
    f32x16 acc2[4];
    #pragma unroll
    for (int hb = 0; hb < 4; ++hb)
        #pragma unroll
        for (int r = 0; r < 16; ++r) acc2[hb][r] = 0.f;

    ISSUE_TILE(0, 0)
    int mA = *(const int*)mbase_b;
    int mB = 0;
    __syncthreads();   // tile 0 staged

    for (int it = 0; it < iters; it += 2) {
        // ---- tile it (buf 0); prefetch it+1 flies during this compute ----
        if (it + 1 < iters) {
            ISSUE_TILE(it + 1, 1)
            mB = *(const int*)(mbase_b + (size_t)(it + 1) * 256);
        }
        attn_tile32(Ks[0], Vs[0], qf, acc2, m_, l_, mA, lane);
        __syncthreads();
        // ---- tile it+1 (buf 1); prefetch it+2 flies during this compute ----
        if (it + 2 < iters) {
            ISSUE_TILE(it + 2, 0)
            mA = *(const int*)(mbase_b + (size_t)(it + 2) * 256);
        }
        if (it + 1 < iters)
            attn_tile32(Ks[1], Vs[1], qf, acc2, m_, l_, mB, lane);
        __syncthreads();
    }
#undef ISSUE_TILE

    // store unnormalized partials: lane writes its q-row, 64 h-values
    const int qrow = b * S_ + q0 + 32 * w + l31;
    float* op = pout + (size_t)(sp * M_ + qrow) * H_;
    #pragma unroll
    for (int hb = 0; hb < 4; ++hb)
        #pragma unroll
        for (int i = 0; i < 8; ++i) {
            const int h = hb * 32 + 2 * (i & 1) + 8 * (i >> 1) + 4 * hi;
            float2 v2 = make_float2(acc2[hb][2 * i], acc2[hb][2 * i + 1]);
            *(float2*)(op + h) = v2;
        }
    if (hi == 0) {
        pm[sp * M_ + qrow] = m_;
        pl[sp * M_ + qrow] = l_;
    }
}

// ---------------------------------------------------------------------------
// Kernel 3: combine KV-split partials and normalize (exp2 domain).
// Vectorized: each thread handles 4 h-values (f32x4 loads/stores).
// ---------------------------------------------------------------------------
__global__ __launch_bounds__(256) void combine_kernel(
    const float* __restrict__ pout, const float* __restrict__ pm,
    const float* __restrict__ pl, float* __restrict__ out, const int nsplit)
{
    const int idx = blockIdx.x * 256 + threadIdx.x;   // < M_*H_/4
    const int row = idx >> 5;          // global row (32 f32x4 per row)
    const int c4  = (idx & 31) * 4;
    float M = -1e30f;
    for (int sp = 0; sp < nsplit; ++sp) M = fmaxf(M, pm[sp * M_ + row]);
    float Z = 0.f;
    f32x4 o = f32x4{0.f, 0.f, 0.f, 0.f};
    for (int sp = 0; sp < nsplit; ++sp) {
        const float wgt = exp2f(pm[sp * M_ + row] - M);
        Z += wgt * pl[sp * M_ + row];
        const f32x4 p = *(const f32x4*)&pout[(size_t)(sp * M_ + row) * H_ + c4];
        o += wgt * p;
    }
    const float inv = 1.f / Z;
    *(f32x4*)&out[(size_t)row * H_ + c4] = o * inv;
}

// ---------------------------------------------------------------------------
extern "C" void kernel_launch(void* const* d_in, const int* in_sizes, int n_in,
                              void* d_out, int out_size, void* d_ws, size_t ws_size,
                              hipStream_t stream)
{
    (void)in_sizes; (void)n_in; (void)out_size;
    // setup_inputs order: inputs, Wk, bk, Wq, bq, Wv, bv, padding_mask
    const float* x  = (const float*)d_in[0];
    const float* Wk = (const float*)d_in[1];
    const float* bk = (const float*)d_in[2];
    const float* Wq = (const float*)d_in[3];
    const float* bq = (const float*)d_in[4];
    const float* Wv = (const float*)d_in[5];
    const float* bv = (const float*)d_in[6];
    const int* mask = (const int*)d_in[7];

    char* ws = (char*)d_ws;
    const size_t qkvBytes = (size_t)M_ * H_ * sizeof(_Float16);   // 4 MB each
    _Float16* qh = (_Float16*)ws;
    _Float16* kh = (_Float16*)(ws + qkvBytes);
    _Float16* vt = (_Float16*)(ws + 2 * qkvBytes);                // [B][H][S]
    _Float16* wh = (_Float16*)(ws + 3 * qkvBytes);                // [3][H][D]
    const size_t whBytes = (size_t)3 * H_ * D_ * sizeof(_Float16);
    char* rest = ws + 3 * qkvBytes + whBytes;

    int nsplit = 4;   // best-measured: 512 blocks = 2/CU, 46 MB partials
    const size_t perSplit = (size_t)M_ * H_ * 4 + 2 * (size_t)M_ * 4;
    while (nsplit > 1 &&
           3 * qkvBytes + whBytes + (size_t)nsplit * perSplit > ws_size) nsplit >>= 1;

    float* pout = (float*)rest;
    float* pm   = (float*)(rest + (size_t)nsplit * M_ * H_ * 4);
    float* pl   = pm + (size_t)nsplit * M_;

    conv_w<<<dim3(3 * H_ * D_ / (256 * 8)), 256, 0, stream>>>(Wq, Wk, Wv, wh);
    proj_kernel<<<dim3(M_ / 64, 3), 256, 0, stream>>>(x, wh, bq, bk, bv, qh, kh, vt);
    attn_kernel<<<dim3(NQT * B_ * nsplit), 256, 0, stream>>>(qh, kh, vt, mask, pout, pm, pl, nsplit);
    combine_kernel<<<dim3(M_ * H_ / (256 * 4)), 256, 0, stream>>>(pout, pm, pl, (float*)d_out, nsplit);
}